// Round 4
// baseline (169.014 us; speedup 1.0000x reference)
//
#include <hip/hip_runtime.h>
#include <hip/hip_bf16.h>

typedef __attribute__((ext_vector_type(8))) short short8;
typedef __attribute__((ext_vector_type(4))) float f32x4;
using u16 = unsigned short;
using u32 = unsigned int;

#define IN_F 4096
#define OUT_F 4096
#define RANK 128

// ---- bf16 pack helpers ----
__device__ inline u32 packi(int a, int b) {  // exact for [-8,7]
    float fa = (float)a, fb = (float)b;
    return (__builtin_bit_cast(u32, fa) >> 16) |
           (__builtin_bit_cast(u32, fb) & 0xFFFF0000u);
}
__device__ inline u32 packf(float a, float b) {  // RNE f32->bf16 pair
    u32 ua = __builtin_bit_cast(u32, a);
    u32 ub = __builtin_bit_cast(u32, b);
    ua = (ua + 0x7FFFu + ((ua >> 16) & 1u)) >> 16;
    ub = (ub + 0x7FFFu + ((ub >> 16) & 1u));
    return ua | (ub & 0xFFFF0000u);
}
__device__ inline u16 f2bf(float f) {
    u32 u = __builtin_bit_cast(u32, f);
    u = (u + 0x7FFFu + ((u >> 16) & 1u)) >> 16;
    return (u16)u;
}

// ws: y 64KB | xb 1MB | bt 1MB
#define WS_Y 0
#define WS_XB 65536
#define WS_BT (65536 + 1048576)

// ---- prep: [0,64) y=x@A (k-split 16, atomics, in-reg f32->bf16)
//            [64,192) x->bf16 | [192,448) B^T -> bt
__global__ __launch_bounds__(512) void prep_kernel(
    const float* __restrict__ x, const float* __restrict__ A,
    const float* __restrict__ B, float* __restrict__ y,
    u16* __restrict__ xb, u16* __restrict__ bt) {
    __shared__ float tile[64 * 33];
    int bid = blockIdx.x, tid = threadIdx.x;
    if (bid < 64) {
        int rt = bid & 3, kq = bid >> 2;
        int lane = tid & 63, wid = tid >> 6;
        int wm = wid >> 1, wn = wid & 1;
        int col = lane & 15, kg = lane >> 4;
        int r = rt * 32 + wn * 16 + col;
        int k0 = kq * 256;
        const float* xq0 = x + (size_t)(wm * 32 + col) * IN_F + k0 + kg * 8;
        const float* xq1 = xq0 + (size_t)16 * IN_F;
        const float* ap = A + (size_t)(k0 + kg * 8) * RANK + r;
        f32x4 acc0 = {0.f, 0.f, 0.f, 0.f}, acc1 = {0.f, 0.f, 0.f, 0.f};
        #pragma unroll
        for (int it = 0; it < 8; ++it) {
            f32x4 xa = *(const f32x4*)(xq0 + it * 32);
            f32x4 xc = *(const f32x4*)(xq0 + it * 32 + 4);
            f32x4 xe = *(const f32x4*)(xq1 + it * 32);
            f32x4 xg = *(const f32x4*)(xq1 + it * 32 + 4);
            union { u32 u[4]; short8 s; } a0, a1, bf;
            a0.u[0] = packf(xa[0], xa[1]); a0.u[1] = packf(xa[2], xa[3]);
            a0.u[2] = packf(xc[0], xc[1]); a0.u[3] = packf(xc[2], xc[3]);
            a1.u[0] = packf(xe[0], xe[1]); a1.u[1] = packf(xe[2], xe[3]);
            a1.u[2] = packf(xg[0], xg[1]); a1.u[3] = packf(xg[2], xg[3]);
            float s0 = ap[(size_t)(it * 32 + 0) * RANK];
            float s1 = ap[(size_t)(it * 32 + 1) * RANK];
            float s2 = ap[(size_t)(it * 32 + 2) * RANK];
            float s3 = ap[(size_t)(it * 32 + 3) * RANK];
            float s4 = ap[(size_t)(it * 32 + 4) * RANK];
            float s5 = ap[(size_t)(it * 32 + 5) * RANK];
            float s6 = ap[(size_t)(it * 32 + 6) * RANK];
            float s7 = ap[(size_t)(it * 32 + 7) * RANK];
            bf.u[0] = packf(s0, s1); bf.u[1] = packf(s2, s3);
            bf.u[2] = packf(s4, s5); bf.u[3] = packf(s6, s7);
            acc0 = __builtin_amdgcn_mfma_f32_16x16x32_bf16(a0.s, bf.s, acc0, 0, 0, 0);
            acc1 = __builtin_amdgcn_mfma_f32_16x16x32_bf16(a1.s, bf.s, acc1, 0, 0, 0);
        }
        int rbase = wm * 32 + kg * 4;
        #pragma unroll
        for (int j = 0; j < 4; ++j) {
            atomicAdd(&y[(rbase + j) * RANK + r], acc0[j]);
            atomicAdd(&y[(rbase + j + 16) * RANK + r], acc1[j]);
        }
    } else if (bid < 192) {
        int b2 = bid - 64;
        const f32x4* xv = (const f32x4*)x;
        int vi = b2 * 1024 + tid * 2;
        f32x4 a = xv[vi], b = xv[vi + 1];
        union { u32 u[4]; short8 s; } p;
        p.u[0] = packf(a[0], a[1]); p.u[1] = packf(a[2], a[3]);
        p.u[2] = packf(b[0], b[1]); p.u[3] = packf(b[2], b[3]);
        *(short8*)(xb + (size_t)vi * 4) = p.s;
    } else {
        int b2 = bid - 192, rt = b2 >> 7, ot = b2 & 127;
        int r0 = rt * 64, o0 = ot * 32;
        for (int u = tid; u < 2048; u += 512) {
            int row = u >> 5, c = u & 31;
            tile[row * 33 + c] = B[(size_t)(r0 + row) * OUT_F + o0 + c];
        }
        __syncthreads();
        for (int u = tid; u < 2048; u += 512) {
            int oo = u >> 6, k = u & 63;
            bt[(size_t)(o0 + oo) * RANK + r0 + k] = f2bf(tile[k * 33 + oo]);
        }
    }
}

// ---- main: BM=64, BN=64, ksplit=4 -> 512 blocks x 512 thr (8 waves)
// No LDS, no barriers: register double-buffer, prefetch distance 2.
#define KCHUNK 1024

__global__ __launch_bounds__(512, 4) void main_kernel(
    const u16* __restrict__ xb, const int* __restrict__ wq,
    const float* __restrict__ scale, const float* __restrict__ bias,
    const float* __restrict__ y, const u16* __restrict__ bt,
    float* __restrict__ out) {
    int tid = threadIdx.x, lane = tid & 63, wid = tid >> 6;
    int wm = wid >> 2, wn = wid & 3;
    int col = lane & 15, kg = lane >> 4;
    int bid = blockIdx.x;
    int ot = bid & 63, mt = (bid >> 6) & 1, kq = bid >> 7;
    int o = ot * 64 + wn * 16 + col;
    int m0 = mt * 64 + wm * 32 + col;
    int k0 = kq * KCHUNK;

    const int* wp = wq + (size_t)o * IN_F + k0 + kg * 8;
    const u16* xp0 = xb + (size_t)m0 * IN_F + k0 + kg * 8;
    const u16* xp1 = xp0 + (size_t)16 * IN_F;

    f32x4 acc0 = {0.f, 0.f, 0.f, 0.f}, acc1 = {0.f, 0.f, 0.f, 0.f};

    int4 wva0, wvb0, wva1, wvb1;
    short8 xv00, xv10, xv01, xv11;

#define LD0(it) { wva0 = *(const int4*)(wp + (it) * 32); \
                  wvb0 = *(const int4*)(wp + (it) * 32 + 4); \
                  xv00 = *(const short8*)(xp0 + (it) * 32); \
                  xv10 = *(const short8*)(xp1 + (it) * 32); }
#define LD1(it) { wva1 = *(const int4*)(wp + (it) * 32); \
                  wvb1 = *(const int4*)(wp + (it) * 32 + 4); \
                  xv01 = *(const short8*)(xp0 + (it) * 32); \
                  xv11 = *(const short8*)(xp1 + (it) * 32); }
#define CMP0 { union { u32 u[4]; short8 s; } bf; \
               bf.u[0] = packi(wva0.x, wva0.y); bf.u[1] = packi(wva0.z, wva0.w); \
               bf.u[2] = packi(wvb0.x, wvb0.y); bf.u[3] = packi(wvb0.z, wvb0.w); \
               acc0 = __builtin_amdgcn_mfma_f32_16x16x32_bf16(xv00, bf.s, acc0, 0, 0, 0); \
               acc1 = __builtin_amdgcn_mfma_f32_16x16x32_bf16(xv10, bf.s, acc1, 0, 0, 0); }
#define CMP1 { union { u32 u[4]; short8 s; } bf; \
               bf.u[0] = packi(wva1.x, wva1.y); bf.u[1] = packi(wva1.z, wva1.w); \
               bf.u[2] = packi(wvb1.x, wvb1.y); bf.u[3] = packi(wvb1.z, wvb1.w); \
               acc0 = __builtin_amdgcn_mfma_f32_16x16x32_bf16(xv01, bf.s, acc0, 0, 0, 0); \
               acc1 = __builtin_amdgcn_mfma_f32_16x16x32_bf16(xv11, bf.s, acc1, 0, 0, 0); }

    LD0(0); LD1(1);
    for (int it2 = 0; it2 < 15; ++it2) {
        CMP0; LD0(2 * it2 + 2);
        CMP1; LD1(2 * it2 + 3);
    }
    CMP0; CMP1;

    float s = scale[o];
    #pragma unroll
    for (int j = 0; j < 4; ++j) { acc0[j] *= s; acc1[j] *= s; }

    if (kq == 0) {  // LoRA + bias added once
        const float* yp0 = y + (size_t)m0 * RANK + kg * 8;
        const float* yp1 = yp0 + 16 * RANK;
        const u16* bp = bt + (size_t)o * RANK + kg * 8;
        #pragma unroll
        for (int ks = 0; ks < RANK; ks += 32) {
            f32x4 ya = *(const f32x4*)(yp0 + ks);
            f32x4 yb = *(const f32x4*)(yp0 + ks + 4);
            f32x4 yc = *(const f32x4*)(yp1 + ks);
            f32x4 yd = *(const f32x4*)(yp1 + ks + 4);
            union { u32 u[4]; short8 s; } af0, af1;
            af0.u[0] = packf(ya[0], ya[1]); af0.u[1] = packf(ya[2], ya[3]);
            af0.u[2] = packf(yb[0], yb[1]); af0.u[3] = packf(yb[2], yb[3]);
            af1.u[0] = packf(yc[0], yc[1]); af1.u[1] = packf(yc[2], yc[3]);
            af1.u[2] = packf(yd[0], yd[1]); af1.u[3] = packf(yd[2], yd[3]);
            short8 bfr = *(const short8*)(bp + ks);
            acc0 = __builtin_amdgcn_mfma_f32_16x16x32_bf16(af0.s, bfr, acc0, 0, 0, 0);
            acc1 = __builtin_amdgcn_mfma_f32_16x16x32_bf16(af1.s, bfr, acc1, 0, 0, 0);
        }
        float bv = bias[o];
        #pragma unroll
        for (int j = 0; j < 4; ++j) { acc0[j] += bv; acc1[j] += bv; }
    }

    int rbase = mt * 64 + wm * 32 + kg * 4;
    float* op = out + (size_t)rbase * OUT_F + o;
    #pragma unroll
    for (int j = 0; j < 4; ++j) {
        atomicAdd(op + (size_t)j * OUT_F, acc0[j]);
        atomicAdd(op + (size_t)(j + 16) * OUT_F, acc1[j]);
    }
}

extern "C" void kernel_launch(void* const* d_in, const int* in_sizes, int n_in,
                              void* d_out, int out_size, void* d_ws, size_t ws_size,
                              hipStream_t stream) {
    const float* x = (const float*)d_in[0];
    const int* wq = (const int*)d_in[1];
    const float* scale = (const float*)d_in[2];
    const float* A = (const float*)d_in[3];
    const float* B = (const float*)d_in[4];
    const float* bias = (const float*)d_in[5];
    float* out = (float*)d_out;

    char* ws = (char*)d_ws;
    float* y = (float*)(ws + WS_Y);
    u16* xb = (u16*)(ws + WS_XB);
    u16* bt = (u16*)(ws + WS_BT);

    hipMemsetAsync(y, 0, 65536, stream);
    hipMemsetAsync(out, 0, (size_t)out_size * sizeof(float), stream);
    prep_kernel<<<448, 512, 0, stream>>>(x, A, B, y, xb, bt);
    main_kernel<<<512, 512, 0, stream>>>(xb, wq, scale, bias, y, bt, out);
}